// Round 9
// baseline (349.347 us; speedup 1.0000x reference)
//
#include <hip/hip_runtime.h>
#include <hip/hip_fp16.h>

// NNUE fused forward, fp16-table + XCD-aligned D-sliced gather.
// (K1) convert ft_weight fp32->fp16 into d_ws (139 MB).
// (K2) merge mw = l1_w + tile(l1f_w) (1.57 MB fp32, exact add).
// (KA) gather: grid = B*8, blockIdx = b*8 + s. Slice s owns a contiguous
//      ~97-unit window of the 770 16-B accumulator units. Round-robin
//      block->XCD dispatch puts slice s on XCD s, so each XCD reads only
//      its 1/8 byte-window of each table row -> per-XCD compulsory misses
//      drop ~8x vs whole-row-per-block (R6/R8 FETCH 850 MB ~= 8x table,
//      measured = per-XCD replication). Partial accs -> fp32 ws (exact).
// (KB) phases B-D per b (256 thr), reading acc from ws; identical FP
//      sequence to the R6-passing kernel (absmax 2.441e-4).
// Tiers: ws >= 242 MB full; >= 140 MB R6 path (sort REVERTED - it hurt);
//        else R5 fp32 kernel.

#define DTOT 3080           // L1 + PSQT floats per ft row
#define TBL16_BYTES 138772480ull   // 22528*3080*2
#define MW_BYTES    1572864ull     // 8*16*3072*4

constexpr float kScale = 127.0f / 128.0f;

__device__ __forceinline__ float clip01(float x) { return fminf(fmaxf(x, 0.0f), 1.0f); }

__device__ __forceinline__ void fma4(float4& a, float s, const float4 v) {
    a.x += s * v.x; a.y += s * v.y; a.z += s * v.z; a.w += s * v.w;
}

__device__ __forceinline__ float4 mix_clip(float u, float th, const float4 w, const float4 b) {
    float4 r;
    r.x = clip01(u * w.x + th * b.x);
    r.y = clip01(u * w.y + th * b.y);
    r.z = clip01(u * w.z + th * b.z);
    r.w = clip01(u * w.w + th * b.w);
    return r;
}

__device__ __forceinline__ float4 mul_scale(const float4 a, const float4 b) {
    float4 r;
    r.x = a.x * b.x * kScale;
    r.y = a.y * b.y * kScale;
    r.z = a.z * b.z * kScale;
    r.w = a.w * b.w * kScale;
    return r;
}

// fp16 16-B unit accumulate; op order bit-identical to R6.
__device__ __forceinline__ void acc_unit(float4& Aa, float4& Ab, const uint4 raw, float v) {
    const __half2* h = (const __half2*)&raw;
    const float2 q0 = __half22float2(h[0]);
    const float2 q1 = __half22float2(h[1]);
    const float2 q2 = __half22float2(h[2]);
    const float2 q3 = __half22float2(h[3]);
    Aa.x += v * q0.x; Aa.y += v * q0.y; Aa.z += v * q1.x; Aa.w += v * q1.y;
    Ab.x += v * q2.x; Ab.y += v * q2.y; Ab.z += v * q3.x; Ab.w += v * q3.y;
}

// ---------- K1: fp32 -> fp16 table conversion ----------
__global__ __launch_bounds__(256) void convert_tbl(const unsigned long long* __restrict__ in,
                                                   uint2* __restrict__ out, int n4)
{
    union Un { unsigned long long u[2]; float f[4]; };
    union Pk { __half2 h2[2]; uint2 u2; };
    for (int i = blockIdx.x * 256 + threadIdx.x; i < n4; i += gridDim.x * 256) {
        Un v;
        v.u[0] = __builtin_nontemporal_load(&in[2 * (size_t)i]);
        v.u[1] = __builtin_nontemporal_load(&in[2 * (size_t)i + 1]);
        Pk p;
        p.h2[0] = __floats2half2_rn(v.f[0], v.f[1]);
        p.h2[1] = __floats2half2_rn(v.f[2], v.f[3]);
        out[i] = p.u2;
    }
}

// ---------- K2: mw = l1_w + tile(l1f_w), float4-wise ----------
__global__ __launch_bounds__(256) void merge_l1(const float* __restrict__ l1w,
                                                const float* __restrict__ l1fw,
                                                float* __restrict__ mw)
{
    const int idx = blockIdx.x * 256 + threadIdx.x;   // 0..98303 float4s
    const float4* a = (const float4*)l1w;
    const float4* f = (const float4*)l1fw;
    float4* o = (float4*)mw;
    const int row = idx / 768;          // 0..127 = c*16+k
    const int k = row & 15;
    const int col = idx - row * 768;
    const float4 x = a[idx];
    const float4 y = f[k * 768 + col];
    float4 r;
    r.x = x.x + y.x; r.y = x.y + y.y; r.z = x.z + y.z; r.w = x.w + y.w;
    o[idx] = r;
}

// ---------- KA: D-sliced gather. blockIdx = b*8 + s  (XCD = s) ----------
// Unit u in [0,770): u<385 white pair u (acc slots 2u,2u+1), u>=385 black
// pair u-385 (slots 2u-770+770 = 2u,2u+1 as well). Slice s covers units
// [96s+min(s,2), ...) of size 97 (s<2) or 96.
__global__ __launch_bounds__(128) void nnue_gather(
    const int* __restrict__ wi, const float* __restrict__ wv,
    const int* __restrict__ bi, const float* __restrict__ bv,
    const __half* __restrict__ tbl, const float* __restrict__ ftb,
    float4* __restrict__ acc_ws)
{
    const int blk = blockIdx.x;
    const int b = blk >> 3;
    const int s = blk & 7;
    const int t = threadIdx.x;

    __shared__ int   sidx[64];
    __shared__ float sval[64];
    if (t < 32)      { sidx[t] = wi[b * 32 + t];      sval[t] = wv[b * 32 + t]; }
    else if (t < 64) { sidx[t] = bi[b * 32 + t - 32]; sval[t] = bv[b * 32 + t - 32]; }
    __syncthreads();

    const int lo = 96 * s + (s < 2 ? s : 2);
    const int size = (s < 2) ? 97 : 96;
    if (t >= size) return;

    const int u = lo + t;
    const bool cb = (u >= 385);            // black?
    const int p = cb ? (u - 385) : u;      // pair index within color

    const float4* fb4 = (const float4*)ftb;
    float4 Aa = fb4[2 * p], Ab = fb4[2 * p + 1];

    #pragma unroll 4
    for (int m = 0; m < 32; ++m) {
        const int row = cb ? sidx[32 + m] : sidx[m];
        const float v = cb ? sval[32 + m] : sval[m];
        const uint4 raw = ((const uint4*)(tbl + (size_t)row * DTOT))[p];
        acc_unit(Aa, Ab, raw, v);
    }

    float4* dst = acc_ws + ((size_t)b * 1540 + 2 * u);
    dst[0] = Aa; dst[1] = Ab;
}

// ---------- KB: phases B-D per batch element (256 threads) ----------
__global__ __launch_bounds__(256) void nnue_mlp(
    const float* __restrict__ us_arr, const float* __restrict__ them_arr,
    const int* __restrict__ pidx, const int* __restrict__ lsidx,
    const float4* __restrict__ acc_ws, const float* __restrict__ mw,
    const float* __restrict__ l1b, const float* __restrict__ l1fb,
    const float* __restrict__ l2w, const float* __restrict__ l2b,
    const float* __restrict__ ow, const float* __restrict__ ob,
    float* __restrict__ out)
{
    const int b = blockIdx.x;
    const int t = threadIdx.x;

    __shared__ float red[4][16];
    __shared__ float l1c[16];
    __shared__ float l1x[30];

    const float usv = us_arr[b];
    const float thv = them_arr[b];
    const int ls = lsidx[b];
    const float4* acc = acc_ws + (size_t)b * 1540;
    const float4* mwbase = (const float4*)mw + (size_t)ls * 16 * 768;

    const int lane = t & 63;
    const int wave = t >> 6;

    float4 fvv[3];
    #pragma unroll
    for (int i = 0; i < 3; ++i) {
        const int col = t + 256 * i;
        const int q = (col >= 384) ? (col - 384) : col;   // 384 != pow2!
        const float4 W0 = acc[q],       W1 = acc[q + 384];
        const float4 B0 = acc[770 + q], B1 = acc[770 + q + 384];
        fvv[i] = (col >= 384)
            ? mul_scale(mix_clip(usv, thv, B0, W0), mix_clip(usv, thv, B1, W1))
            : mul_scale(mix_clip(usv, thv, W0, B0), mix_clip(usv, thv, W1, B1));
    }

    #pragma unroll
    for (int half = 0; half < 2; ++half) {
        float acck[8];
        #pragma unroll
        for (int k = 0; k < 8; ++k) acck[k] = 0.f;

        #pragma unroll
        for (int i = 0; i < 3; ++i) {
            const int col = t + 256 * i;
            const float4 fv = fvv[i];
            #pragma unroll
            for (int k = 0; k < 8; ++k) {
                const float4 w1 = mwbase[(size_t)(half * 8 + k) * 768 + col];
                acck[k] += fv.x * w1.x + fv.y * w1.y + fv.z * w1.z + fv.w * w1.w;
            }
        }

        #pragma unroll
        for (int k = 0; k < 8; ++k) {
            #pragma unroll
            for (int off = 32; off > 0; off >>= 1)
                acck[k] += __shfl_xor(acck[k], off, 64);
        }
        if (lane == 0) {
            #pragma unroll
            for (int k = 0; k < 8; ++k) red[wave][half * 8 + k] = acck[k];
        }
    }
    __syncthreads();

    if (t < 16) {
        l1c[t] = red[0][t] + red[1][t] + red[2][t] + red[3][t]
               + l1b[ls * 16 + t] + l1fb[t];
    }
    __syncthreads();

    if (t < 15) {
        const float v = l1c[t];
        l1x[t]      = clip01(v * v * kScale);
        l1x[15 + t] = clip01(v);
    }
    __syncthreads();

    float partial = 0.f;
    if (t < 32) {
        const float* r2 = l2w + (size_t)(ls * 32 + t) * 30;
        float s2 = l2b[ls * 32 + t];
        #pragma unroll
        for (int i = 0; i < 30; ++i) s2 += l1x[i] * r2[i];
        partial = clip01(s2) * ow[ls * 32 + t];
    }
    #pragma unroll
    for (int off = 16; off > 0; off >>= 1)
        partial += __shfl_xor(partial, off, 64);

    if (t == 0) {
        const int pi = pidx[b];
        const float* pw = (const float*)(acc + 768);    // white psqt (slots 768,769)
        const float* pb = (const float*)(acc + 1538);   // black psqt
        out[b] = partial + ob[ls] + l1c[15]
               + (pw[pi] - pb[pi]) * (usv - 0.5f);
    }
}

// ---------- Tier 2: R6 kernel (fp16 table, whole-row blocks, NO sort) ----------
__global__ __launch_bounds__(512, 2) void nnue_fp16(
    const float* __restrict__ us_arr, const float* __restrict__ them_arr,
    const int* __restrict__ wi, const float* __restrict__ wv,
    const int* __restrict__ bi, const float* __restrict__ bv,
    const int* __restrict__ pidx, const int* __restrict__ lsidx,
    const __half* __restrict__ tbl, const float* __restrict__ ftb,
    const float* __restrict__ mw,
    const float* __restrict__ l1b, const float* __restrict__ l1fb,
    const float* __restrict__ l2w, const float* __restrict__ l2b,
    const float* __restrict__ ow, const float* __restrict__ ob,
    float* __restrict__ out)
{
    const int b = blockIdx.x;
    const int t = threadIdx.x;

    __shared__ float4 lds_acc[1540];
    __shared__ int   sidx[64];
    __shared__ float sval[64];
    __shared__ float red[4][16];
    __shared__ float l1c[16];
    __shared__ float l1x[30];

    if (t < 32)      { sidx[t] = wi[b * 32 + t];      sval[t] = wv[b * 32 + t]; }
    else if (t < 64) { sidx[t] = bi[b * 32 + t - 32]; sval[t] = bv[b * 32 + t - 32]; }
    __syncthreads();

    const int u0 = t;
    const bool c0 = (u0 >= 385);
    const int p0 = c0 ? (u0 - 385) : u0;
    const bool has1 = (t < 258);
    const int p1 = t + 127;

    const float4* fb4 = (const float4*)ftb;
    float4 A0a = fb4[2 * p0], A0b = fb4[2 * p0 + 1];
    float4 A1a = has1 ? fb4[2 * p1] : float4{0.f, 0.f, 0.f, 0.f};
    float4 A1b = has1 ? fb4[2 * p1 + 1] : float4{0.f, 0.f, 0.f, 0.f};

    #pragma unroll 4
    for (int m = 0; m < 32; ++m) {
        const __half* rowW = tbl + (size_t)sidx[m]      * DTOT;
        const __half* rowB = tbl + (size_t)sidx[32 + m] * DTOT;
        const float vw = sval[m], vb = sval[32 + m];

        const float v0 = c0 ? vb : vw;
        const uint4 raw0 = ((const uint4*)(c0 ? rowB : rowW))[p0];
        acc_unit(A0a, A0b, raw0, v0);
        if (has1) {
            const uint4 raw1 = ((const uint4*)rowB)[p1];
            acc_unit(A1a, A1b, raw1, vb);
        }
    }

    {
        const int g0 = (c0 ? 770 : 0) + 2 * p0;
        lds_acc[g0] = A0a; lds_acc[g0 + 1] = A0b;
        if (has1) {
            const int g1 = 770 + 2 * p1;
            lds_acc[g1] = A1a; lds_acc[g1 + 1] = A1b;
        }
    }
    __syncthreads();

    const float usv = us_arr[b];
    const float thv = them_arr[b];
    const int ls = lsidx[b];
    const float4* mwbase = (const float4*)mw + (size_t)ls * 16 * 768;

    const int lane = t & 63;
    const int wave = t >> 6;

    if (t < 256) {
        float4 fvv[3];
        #pragma unroll
        for (int i = 0; i < 3; ++i) {
            const int col = t + 256 * i;
            const int q = (col >= 384) ? (col - 384) : col;
            const float4 W0 = lds_acc[q],       W1 = lds_acc[q + 384];
            const float4 B0 = lds_acc[770 + q], B1 = lds_acc[770 + q + 384];
            fvv[i] = (col >= 384)
                ? mul_scale(mix_clip(usv, thv, B0, W0), mix_clip(usv, thv, B1, W1))
                : mul_scale(mix_clip(usv, thv, W0, B0), mix_clip(usv, thv, W1, B1));
        }

        #pragma unroll
        for (int half = 0; half < 2; ++half) {
            float acck[8];
            #pragma unroll
            for (int k = 0; k < 8; ++k) acck[k] = 0.f;

            #pragma unroll
            for (int i = 0; i < 3; ++i) {
                const int col = t + 256 * i;
                const float4 fv = fvv[i];
                #pragma unroll
                for (int k = 0; k < 8; ++k) {
                    const float4 w1 = mwbase[(size_t)(half * 8 + k) * 768 + col];
                    acck[k] += fv.x * w1.x + fv.y * w1.y + fv.z * w1.z + fv.w * w1.w;
                }
            }

            #pragma unroll
            for (int k = 0; k < 8; ++k) {
                #pragma unroll
                for (int off = 32; off > 0; off >>= 1)
                    acck[k] += __shfl_xor(acck[k], off, 64);
            }
            if (lane == 0) {
                #pragma unroll
                for (int k = 0; k < 8; ++k) red[wave][half * 8 + k] = acck[k];
            }
        }
    }
    __syncthreads();

    if (t < 16) {
        l1c[t] = red[0][t] + red[1][t] + red[2][t] + red[3][t]
               + l1b[ls * 16 + t] + l1fb[t];
    }
    __syncthreads();

    if (t < 15) {
        const float v = l1c[t];
        l1x[t]      = clip01(v * v * kScale);
        l1x[15 + t] = clip01(v);
    }
    __syncthreads();

    float partial = 0.f;
    if (t < 32) {
        const float* r2 = l2w + (size_t)(ls * 32 + t) * 30;
        float s2 = l2b[ls * 32 + t];
        #pragma unroll
        for (int i = 0; i < 30; ++i) s2 += l1x[i] * r2[i];
        partial = clip01(s2) * ow[ls * 32 + t];
    }
    #pragma unroll
    for (int off = 16; off > 0; off >>= 1)
        partial += __shfl_xor(partial, off, 64);

    if (t == 0) {
        const int pi = pidx[b];
        const float* pw = (const float*)&lds_acc[768];
        const float* pb = (const float*)&lds_acc[770 + 768];
        out[b] = partial + ob[ls] + l1c[15]
               + (pw[pi] - pb[pi]) * (usv - 0.5f);
    }
}

// ---------- Tier 3: R5 fp32 kernel verbatim ----------
__global__ __launch_bounds__(512, 2) void nnue_fused(
    const float* __restrict__ us_arr, const float* __restrict__ them_arr,
    const int* __restrict__ wi, const float* __restrict__ wv,
    const int* __restrict__ bi, const float* __restrict__ bv,
    const int* __restrict__ pidx, const int* __restrict__ lsidx,
    const float* __restrict__ ftw, const float* __restrict__ ftb,
    const float* __restrict__ l1w, const float* __restrict__ l1b,
    const float* __restrict__ l1fw, const float* __restrict__ l1fb,
    const float* __restrict__ l2w, const float* __restrict__ l2b,
    const float* __restrict__ ow, const float* __restrict__ ob,
    float* __restrict__ out)
{
    const int b = blockIdx.x;
    const int t = threadIdx.x;

    __shared__ float4 lds_acc[1540];
    __shared__ int   sidx[64];
    __shared__ float sval[64];
    __shared__ float red[4][16];
    __shared__ float l1c[16];
    __shared__ float l1x[30];

    if (t < 32)      { sidx[t] = wi[b * 32 + t];      sval[t] = wv[b * 32 + t]; }
    else if (t < 64) { sidx[t] = bi[b * 32 + t - 32]; sval[t] = bv[b * 32 + t - 32]; }
    __syncthreads();

    const int g0 = t, g1 = t + 512, g2 = t + 1024;
    const int c1 = (g1 >= 770);
    const int s0 = t;
    const int s1 = c1 ? (g1 - 770) : g1;
    const int s2 = g2 - 770;
    const bool has3 = (t < 4);
    const int s3 = 766 + t;

    const float4* fb4 = (const float4*)ftb;
    float4 a0 = fb4[s0], a1 = fb4[s1], a2 = fb4[s2];
    float4 a3 = has3 ? fb4[s3] : float4{0.f, 0.f, 0.f, 0.f};

    #pragma unroll 2
    for (int m = 0; m < 32; ++m) {
        const float4* rw = (const float4*)(ftw + (size_t)sidx[m]      * DTOT);
        const float4* rb = (const float4*)(ftw + (size_t)sidx[32 + m] * DTOT);
        const float vw = sval[m], vb = sval[32 + m];

        fma4(a0, vw, rw[s0]);
        const float4* p1 = c1 ? rb : rw;
        fma4(a1, c1 ? vb : vw, p1[s1]);
        fma4(a2, vb, rb[s2]);
        if (has3) fma4(a3, vb, rb[s3]);
    }

    lds_acc[g0] = a0;
    lds_acc[g1] = a1;
    lds_acc[g2] = a2;
    if (has3) lds_acc[1536 + t] = a3;
    __syncthreads();

    const float usv = us_arr[b];
    const float thv = them_arr[b];
    const int ls = lsidx[b];

    const float4* w1base = (const float4*)(l1w + (size_t)ls * 16 * 3072);
    const float4* w2base = (const float4*)l1fw;

    const int lane = t & 63;
    const int wave = t >> 6;

    if (t < 256) {
        float acc[16];
        #pragma unroll
        for (int k = 0; k < 16; ++k) acc[k] = 0.f;

        #pragma unroll
        for (int i = 0; i < 3; ++i) {
            const int col = t + 256 * i;
            const int q = (col >= 384) ? (col - 384) : col;
            const float4 W0 = lds_acc[q],       W1 = lds_acc[q + 384];
            const float4 B0 = lds_acc[770 + q], B1 = lds_acc[770 + q + 384];
            const float4 fv = (col >= 384)
                ? mul_scale(mix_clip(usv, thv, B0, W0), mix_clip(usv, thv, B1, W1))
                : mul_scale(mix_clip(usv, thv, W0, B0), mix_clip(usv, thv, W1, B1));
            #pragma unroll
            for (int k = 0; k < 16; ++k) {
                const float4 w1 = w1base[(size_t)k * 768 + col];
                const float4 w2 = w2base[(size_t)k * 768 + col];
                acc[k] += fv.x * (w1.x + w2.x) + fv.y * (w1.y + w2.y)
                        + fv.z * (w1.z + w2.z) + fv.w * (w1.w + w2.w);
            }
        }

        #pragma unroll
        for (int k = 0; k < 16; ++k) {
            #pragma unroll
            for (int off = 32; off > 0; off >>= 1)
                acc[k] += __shfl_xor(acc[k], off, 64);
        }
        if (lane == 0) {
            #pragma unroll
            for (int k = 0; k < 16; ++k) red[wave][k] = acc[k];
        }
    }
    __syncthreads();

    if (t < 16) {
        l1c[t] = red[0][t] + red[1][t] + red[2][t] + red[3][t]
               + l1b[ls * 16 + t] + l1fb[t];
    }
    __syncthreads();

    if (t < 15) {
        const float v = l1c[t];
        l1x[t]      = clip01(v * v * kScale);
        l1x[15 + t] = clip01(v);
    }
    __syncthreads();

    float partial = 0.f;
    if (t < 32) {
        const float* r2 = l2w + (size_t)(ls * 32 + t) * 30;
        float s2 = l2b[ls * 32 + t];
        #pragma unroll
        for (int i = 0; i < 30; ++i) s2 += l1x[i] * r2[i];
        partial = clip01(s2) * ow[ls * 32 + t];
    }
    #pragma unroll
    for (int off = 16; off > 0; off >>= 1)
        partial += __shfl_xor(partial, off, 64);

    if (t == 0) {
        const int pi = pidx[b];
        const float* pw = (const float*)&lds_acc[768];
        const float* pb = (const float*)&lds_acc[770 + 768];
        out[b] = partial + ob[ls] + l1c[15]
               + (pw[pi] - pb[pi]) * (usv - 0.5f);
    }
}

extern "C" void kernel_launch(void* const* d_in, const int* in_sizes, int n_in,
                              void* d_out, int out_size, void* d_ws, size_t ws_size,
                              hipStream_t stream) {
    const float* us   = (const float*)d_in[0];
    const float* them = (const float*)d_in[1];
    const int*   wi   = (const int*)d_in[2];
    const float* wv   = (const float*)d_in[3];
    const int*   bi   = (const int*)d_in[4];
    const float* bv   = (const float*)d_in[5];
    const int*   pidx = (const int*)d_in[6];
    const int*   ls   = (const int*)d_in[7];
    const float* ftw  = (const float*)d_in[8];
    const float* ftb  = (const float*)d_in[9];
    const float* l1w  = (const float*)d_in[10];
    const float* l1b  = (const float*)d_in[11];
    const float* l1fw = (const float*)d_in[12];
    const float* l1fb = (const float*)d_in[13];
    const float* l2w  = (const float*)d_in[14];
    const float* l2b  = (const float*)d_in[15];
    const float* ow   = (const float*)d_in[16];
    const float* ob   = (const float*)d_in[17];
    float* out = (float*)d_out;

    const int B = in_sizes[0];
    const size_t acc_bytes = (size_t)B * 1540 * 16;
    const size_t need_fp16 = TBL16_BYTES + MW_BYTES;
    const size_t need_full = need_fp16 + acc_bytes;

    if (ws_size >= need_full) {
        __half* tbl16 = (__half*)d_ws;
        float*  mw    = (float*)((char*)d_ws + TBL16_BYTES);
        float4* accw  = (float4*)((char*)d_ws + TBL16_BYTES + MW_BYTES);
        convert_tbl<<<2048, 256, 0, stream>>>((const unsigned long long*)ftw, (uint2*)d_ws, 17346560);
        merge_l1<<<384, 256, 0, stream>>>(l1w, l1fw, mw);
        nnue_gather<<<B * 8, 128, 0, stream>>>(wi, wv, bi, bv, tbl16, ftb, accw);
        nnue_mlp<<<B, 256, 0, stream>>>(us, them, pidx, ls, accw, mw,
                                        l1b, l1fb, l2w, l2b, ow, ob, out);
    } else if (ws_size >= need_fp16) {
        __half* tbl16 = (__half*)d_ws;
        float*  mw    = (float*)((char*)d_ws + TBL16_BYTES);
        convert_tbl<<<2048, 256, 0, stream>>>((const unsigned long long*)ftw, (uint2*)d_ws, 17346560);
        merge_l1<<<384, 256, 0, stream>>>(l1w, l1fw, mw);
        nnue_fp16<<<B, 512, 0, stream>>>(us, them, wi, wv, bi, bv, pidx, ls,
                                         tbl16, ftb, mw, l1b, l1fb,
                                         l2w, l2b, ow, ob, out);
    } else {
        nnue_fused<<<B, 512, 0, stream>>>(us, them, wi, wv, bi, bv, pidx, ls,
                                          ftw, ftb, l1w, l1b, l1fw, l1fb,
                                          l2w, l2b, ow, ob, out);
    }
}

// Round 10
// 348.941 us; speedup vs baseline: 1.0012x; 1.0012x over previous
//
#include <hip/hip_runtime.h>
#include <hip/hip_fp16.h>

// NNUE fused forward, fp16-table + color-paired XCD-affine sliced gather.
// (K1) convert ft_weight fp32->fp16 into d_ws (139 MB).
// (K2) merge mw = l1_w + tile(l1f_w) (1.57 MB fp32, exact add).
// (KA) gather: work item = (slice s, 4 b's). Slice s = table byte-window
//      (float4-pairs [w_lo, w_lo+nw)) applied to BOTH colors (white unit w,
//      black unit 385+w) -> per-XCD table footprint = 17.3 MB, aggregate
//      compulsory = ONE table sweep (139 MB), vs R9's 2x color replication.
//      TRUE XCD affinity: block reads HW_REG_XCC_ID and claims work for its
//      own XCD's slice via per-slice atomic counters (probe all 8 slices ->
//      exactly-once completion regardless of dispatch->XCD mapping).
// (KB) phases B-D per b (256 thr) reading fp32 partials from ws; identical
//      FP sequence to R6/R9 (absmax 2.441e-4, 10x under threshold).
// Tiers: ws >= ~242 MB full; >= 140 MB R6 fused path; else R5 fp32 kernel.

#define DTOT 3080           // L1 + PSQT floats per ft row
#define TBL16_BYTES 138772480ull   // 22528*3080*2
#define MW_BYTES    1572864ull     // 8*16*3072*4

constexpr float kScale = 127.0f / 128.0f;

__device__ __forceinline__ float clip01(float x) { return fminf(fmaxf(x, 0.0f), 1.0f); }

__device__ __forceinline__ void fma4(float4& a, float s, const float4 v) {
    a.x += s * v.x; a.y += s * v.y; a.z += s * v.z; a.w += s * v.w;
}

__device__ __forceinline__ float4 mix_clip(float u, float th, const float4 w, const float4 b) {
    float4 r;
    r.x = clip01(u * w.x + th * b.x);
    r.y = clip01(u * w.y + th * b.y);
    r.z = clip01(u * w.z + th * b.z);
    r.w = clip01(u * w.w + th * b.w);
    return r;
}

__device__ __forceinline__ float4 mul_scale(const float4 a, const float4 b) {
    float4 r;
    r.x = a.x * b.x * kScale;
    r.y = a.y * b.y * kScale;
    r.z = a.z * b.z * kScale;
    r.w = a.w * b.w * kScale;
    return r;
}

// fp16 16-B unit accumulate; op order bit-identical to R6/R9.
__device__ __forceinline__ void acc_unit(float4& Aa, float4& Ab, const uint4 raw, float v) {
    const __half2* h = (const __half2*)&raw;
    const float2 q0 = __half22float2(h[0]);
    const float2 q1 = __half22float2(h[1]);
    const float2 q2 = __half22float2(h[2]);
    const float2 q3 = __half22float2(h[3]);
    Aa.x += v * q0.x; Aa.y += v * q0.y; Aa.z += v * q1.x; Aa.w += v * q1.y;
    Ab.x += v * q2.x; Ab.y += v * q2.y; Ab.z += v * q3.x; Ab.w += v * q3.y;
}

// ---------- K1: fp32 -> fp16 table conversion ----------
__global__ __launch_bounds__(256) void convert_tbl(const unsigned long long* __restrict__ in,
                                                   uint2* __restrict__ out, int n4)
{
    union Un { unsigned long long u[2]; float f[4]; };
    union Pk { __half2 h2[2]; uint2 u2; };
    for (int i = blockIdx.x * 256 + threadIdx.x; i < n4; i += gridDim.x * 256) {
        Un v;
        v.u[0] = __builtin_nontemporal_load(&in[2 * (size_t)i]);
        v.u[1] = __builtin_nontemporal_load(&in[2 * (size_t)i + 1]);
        Pk p;
        p.h2[0] = __floats2half2_rn(v.f[0], v.f[1]);
        p.h2[1] = __floats2half2_rn(v.f[2], v.f[3]);
        out[i] = p.u2;
    }
}

// ---------- K2: mw = l1_w + tile(l1f_w), float4-wise ----------
__global__ __launch_bounds__(256) void merge_l1(const float* __restrict__ l1w,
                                                const float* __restrict__ l1fw,
                                                float* __restrict__ mw)
{
    const int idx = blockIdx.x * 256 + threadIdx.x;   // 0..98303 float4s
    const float4* a = (const float4*)l1w;
    const float4* f = (const float4*)l1fw;
    float4* o = (float4*)mw;
    const int row = idx / 768;          // 0..127 = c*16+k
    const int k = row & 15;
    const int col = idx - row * 768;
    const float4 x = a[idx];
    const float4 y = f[k * 768 + col];
    float4 r;
    r.x = x.x + y.x; r.y = x.y + y.y; r.z = x.z + y.z; r.w = x.w + y.w;
    o[idx] = r;
}

// ---------- KA: color-paired sliced gather with XCD-affine claiming ----------
// Window slices over w in [0,385): s=0 -> [0,49), s>=1 -> [48s+1, 48s+49).
// Thread layout: 256 thr = 4 b-groups x 64 lanes; lane t64 handles window
// w = w_lo + t64 (if t64 < nw) for BOTH colors of its b.
__global__ __launch_bounds__(256) void nnue_gather(
    const int* __restrict__ wi, const float* __restrict__ wv,
    const int* __restrict__ bi, const float* __restrict__ bv,
    const __half* __restrict__ tbl, const float* __restrict__ ftb,
    float4* __restrict__ acc_ws, int* __restrict__ cnt, int NI)
{
    __shared__ int   s_item;
    __shared__ int   sidx[4][64];
    __shared__ float sval[4][64];

    if (threadIdx.x == 0) {
        unsigned int xid;
        asm volatile("s_getreg_b32 %0, hwreg(HW_REG_XCC_ID)" : "=s"(xid));
        xid &= 7;
        int item = -1;
        for (int k = 0; k < 8; ++k) {
            const int s = (xid + k) & 7;
            const int c = atomicAdd(&cnt[s], 1);
            if (c < NI) { item = s * NI + c; break; }
        }
        s_item = item;
    }
    __syncthreads();
    const int item = s_item;
    if (item < 0) return;

    const int s = item / NI;
    const int bbase = (item - s * NI) * 4;
    const int w_lo = (s == 0) ? 0 : (48 * s + 1);
    const int nw   = (s == 0) ? 49 : 48;

    const int t = threadIdx.x;
    const int bl = t >> 6;
    const int t64 = t & 63;
    {
        const int b = bbase + bl;
        sidx[bl][t64] = (t64 < 32) ? wi[b * 32 + t64] : bi[b * 32 + (t64 - 32)];
        sval[bl][t64] = (t64 < 32) ? wv[b * 32 + t64] : bv[b * 32 + (t64 - 32)];
    }
    __syncthreads();

    if (t64 < nw) {
        const int b = bbase + bl;
        const int w = w_lo + t64;              // window index 0..384
        const float4* fb4 = (const float4*)ftb;
        const float4 bias_a = fb4[2 * w], bias_b = fb4[2 * w + 1];
        float4 Wa = bias_a, Wb = bias_b;       // white unit u = w
        float4 Ba = bias_a, Bb = bias_b;       // black unit u = 385 + w

        #pragma unroll 4
        for (int m = 0; m < 32; ++m) {
            const int   rw = sidx[bl][m];      const float vw = sval[bl][m];
            const int   rb = sidx[bl][32 + m]; const float vb = sval[bl][32 + m];
            const uint4 rawW = ((const uint4*)(tbl + (size_t)rw * DTOT))[w];
            const uint4 rawB = ((const uint4*)(tbl + (size_t)rb * DTOT))[w];
            acc_unit(Wa, Wb, rawW, vw);
            acc_unit(Ba, Bb, rawB, vb);
        }

        float4* dst = acc_ws + (size_t)b * 1540;
        dst[2 * w]     = Wa;  dst[2 * w + 1]     = Wb;
        const int ub = 385 + w;
        dst[2 * ub]    = Ba;  dst[2 * ub + 1]    = Bb;
    }
}

// ---------- KB: phases B-D per batch element (256 threads) ----------
__global__ __launch_bounds__(256) void nnue_mlp(
    const float* __restrict__ us_arr, const float* __restrict__ them_arr,
    const int* __restrict__ pidx, const int* __restrict__ lsidx,
    const float4* __restrict__ acc_ws, const float* __restrict__ mw,
    const float* __restrict__ l1b, const float* __restrict__ l1fb,
    const float* __restrict__ l2w, const float* __restrict__ l2b,
    const float* __restrict__ ow, const float* __restrict__ ob,
    float* __restrict__ out)
{
    const int b = blockIdx.x;
    const int t = threadIdx.x;

    __shared__ float red[4][16];
    __shared__ float l1c[16];
    __shared__ float l1x[30];

    const float usv = us_arr[b];
    const float thv = them_arr[b];
    const int ls = lsidx[b];
    const float4* acc = acc_ws + (size_t)b * 1540;
    const float4* mwbase = (const float4*)mw + (size_t)ls * 16 * 768;

    const int lane = t & 63;
    const int wave = t >> 6;

    float4 fvv[3];
    #pragma unroll
    for (int i = 0; i < 3; ++i) {
        const int col = t + 256 * i;
        const int q = (col >= 384) ? (col - 384) : col;   // 384 != pow2!
        const float4 W0 = acc[q],       W1 = acc[q + 384];
        const float4 B0 = acc[770 + q], B1 = acc[770 + q + 384];
        fvv[i] = (col >= 384)
            ? mul_scale(mix_clip(usv, thv, B0, W0), mix_clip(usv, thv, B1, W1))
            : mul_scale(mix_clip(usv, thv, W0, B0), mix_clip(usv, thv, W1, B1));
    }

    #pragma unroll
    for (int half = 0; half < 2; ++half) {
        float acck[8];
        #pragma unroll
        for (int k = 0; k < 8; ++k) acck[k] = 0.f;

        #pragma unroll
        for (int i = 0; i < 3; ++i) {
            const int col = t + 256 * i;
            const float4 fv = fvv[i];
            #pragma unroll
            for (int k = 0; k < 8; ++k) {
                const float4 w1 = mwbase[(size_t)(half * 8 + k) * 768 + col];
                acck[k] += fv.x * w1.x + fv.y * w1.y + fv.z * w1.z + fv.w * w1.w;
            }
        }

        #pragma unroll
        for (int k = 0; k < 8; ++k) {
            #pragma unroll
            for (int off = 32; off > 0; off >>= 1)
                acck[k] += __shfl_xor(acck[k], off, 64);
        }
        if (lane == 0) {
            #pragma unroll
            for (int k = 0; k < 8; ++k) red[wave][half * 8 + k] = acck[k];
        }
    }
    __syncthreads();

    if (t < 16) {
        l1c[t] = red[0][t] + red[1][t] + red[2][t] + red[3][t]
               + l1b[ls * 16 + t] + l1fb[t];
    }
    __syncthreads();

    if (t < 15) {
        const float v = l1c[t];
        l1x[t]      = clip01(v * v * kScale);
        l1x[15 + t] = clip01(v);
    }
    __syncthreads();

    float partial = 0.f;
    if (t < 32) {
        const float* r2 = l2w + (size_t)(ls * 32 + t) * 30;
        float s2 = l2b[ls * 32 + t];
        #pragma unroll
        for (int i = 0; i < 30; ++i) s2 += l1x[i] * r2[i];
        partial = clip01(s2) * ow[ls * 32 + t];
    }
    #pragma unroll
    for (int off = 16; off > 0; off >>= 1)
        partial += __shfl_xor(partial, off, 64);

    if (t == 0) {
        const int pi = pidx[b];
        const float* pw = (const float*)(acc + 768);    // white psqt (slots 768,769)
        const float* pb = (const float*)(acc + 1538);   // black psqt
        out[b] = partial + ob[ls] + l1c[15]
               + (pw[pi] - pb[pi]) * (usv - 0.5f);
    }
}

// ---------- Tier 2: R6 fused kernel (fp16 table, whole-row blocks) ----------
__global__ __launch_bounds__(512, 2) void nnue_fp16(
    const float* __restrict__ us_arr, const float* __restrict__ them_arr,
    const int* __restrict__ wi, const float* __restrict__ wv,
    const int* __restrict__ bi, const float* __restrict__ bv,
    const int* __restrict__ pidx, const int* __restrict__ lsidx,
    const __half* __restrict__ tbl, const float* __restrict__ ftb,
    const float* __restrict__ mw,
    const float* __restrict__ l1b, const float* __restrict__ l1fb,
    const float* __restrict__ l2w, const float* __restrict__ l2b,
    const float* __restrict__ ow, const float* __restrict__ ob,
    float* __restrict__ out)
{
    const int b = blockIdx.x;
    const int t = threadIdx.x;

    __shared__ float4 lds_acc[1540];
    __shared__ int   sidx[64];
    __shared__ float sval[64];
    __shared__ float red[4][16];
    __shared__ float l1c[16];
    __shared__ float l1x[30];

    if (t < 32)      { sidx[t] = wi[b * 32 + t];      sval[t] = wv[b * 32 + t]; }
    else if (t < 64) { sidx[t] = bi[b * 32 + t - 32]; sval[t] = bv[b * 32 + t - 32]; }
    __syncthreads();

    const int u0 = t;
    const bool c0 = (u0 >= 385);
    const int p0 = c0 ? (u0 - 385) : u0;
    const bool has1 = (t < 258);
    const int p1 = t + 127;

    const float4* fb4 = (const float4*)ftb;
    float4 A0a = fb4[2 * p0], A0b = fb4[2 * p0 + 1];
    float4 A1a = has1 ? fb4[2 * p1] : float4{0.f, 0.f, 0.f, 0.f};
    float4 A1b = has1 ? fb4[2 * p1 + 1] : float4{0.f, 0.f, 0.f, 0.f};

    #pragma unroll 4
    for (int m = 0; m < 32; ++m) {
        const __half* rowW = tbl + (size_t)sidx[m]      * DTOT;
        const __half* rowB = tbl + (size_t)sidx[32 + m] * DTOT;
        const float vw = sval[m], vb = sval[32 + m];

        const float v0 = c0 ? vb : vw;
        const uint4 raw0 = ((const uint4*)(c0 ? rowB : rowW))[p0];
        acc_unit(A0a, A0b, raw0, v0);
        if (has1) {
            const uint4 raw1 = ((const uint4*)rowB)[p1];
            acc_unit(A1a, A1b, raw1, vb);
        }
    }

    {
        const int g0 = (c0 ? 770 : 0) + 2 * p0;
        lds_acc[g0] = A0a; lds_acc[g0 + 1] = A0b;
        if (has1) {
            const int g1 = 770 + 2 * p1;
            lds_acc[g1] = A1a; lds_acc[g1 + 1] = A1b;
        }
    }
    __syncthreads();

    const float usv = us_arr[b];
    const float thv = them_arr[b];
    const int ls = lsidx[b];
    const float4* mwbase = (const float4*)mw + (size_t)ls * 16 * 768;

    const int lane = t & 63;
    const int wave = t >> 6;

    if (t < 256) {
        float4 fvv[3];
        #pragma unroll
        for (int i = 0; i < 3; ++i) {
            const int col = t + 256 * i;
            const int q = (col >= 384) ? (col - 384) : col;
            const float4 W0 = lds_acc[q],       W1 = lds_acc[q + 384];
            const float4 B0 = lds_acc[770 + q], B1 = lds_acc[770 + q + 384];
            fvv[i] = (col >= 384)
                ? mul_scale(mix_clip(usv, thv, B0, W0), mix_clip(usv, thv, B1, W1))
                : mul_scale(mix_clip(usv, thv, W0, B0), mix_clip(usv, thv, W1, B1));
        }

        #pragma unroll
        for (int half = 0; half < 2; ++half) {
            float acck[8];
            #pragma unroll
            for (int k = 0; k < 8; ++k) acck[k] = 0.f;

            #pragma unroll
            for (int i = 0; i < 3; ++i) {
                const int col = t + 256 * i;
                const float4 fv = fvv[i];
                #pragma unroll
                for (int k = 0; k < 8; ++k) {
                    const float4 w1 = mwbase[(size_t)(half * 8 + k) * 768 + col];
                    acck[k] += fv.x * w1.x + fv.y * w1.y + fv.z * w1.z + fv.w * w1.w;
                }
            }

            #pragma unroll
            for (int k = 0; k < 8; ++k) {
                #pragma unroll
                for (int off = 32; off > 0; off >>= 1)
                    acck[k] += __shfl_xor(acck[k], off, 64);
            }
            if (lane == 0) {
                #pragma unroll
                for (int k = 0; k < 8; ++k) red[wave][half * 8 + k] = acck[k];
            }
        }
    }
    __syncthreads();

    if (t < 16) {
        l1c[t] = red[0][t] + red[1][t] + red[2][t] + red[3][t]
               + l1b[ls * 16 + t] + l1fb[t];
    }
    __syncthreads();

    if (t < 15) {
        const float v = l1c[t];
        l1x[t]      = clip01(v * v * kScale);
        l1x[15 + t] = clip01(v);
    }
    __syncthreads();

    float partial = 0.f;
    if (t < 32) {
        const float* r2 = l2w + (size_t)(ls * 32 + t) * 30;
        float s2 = l2b[ls * 32 + t];
        #pragma unroll
        for (int i = 0; i < 30; ++i) s2 += l1x[i] * r2[i];
        partial = clip01(s2) * ow[ls * 32 + t];
    }
    #pragma unroll
    for (int off = 16; off > 0; off >>= 1)
        partial += __shfl_xor(partial, off, 64);

    if (t == 0) {
        const int pi = pidx[b];
        const float* pw = (const float*)&lds_acc[768];
        const float* pb = (const float*)&lds_acc[770 + 768];
        out[b] = partial + ob[ls] + l1c[15]
               + (pw[pi] - pb[pi]) * (usv - 0.5f);
    }
}

// ---------- Tier 3: R5 fp32 kernel verbatim ----------
__global__ __launch_bounds__(512, 2) void nnue_fused(
    const float* __restrict__ us_arr, const float* __restrict__ them_arr,
    const int* __restrict__ wi, const float* __restrict__ wv,
    const int* __restrict__ bi, const float* __restrict__ bv,
    const int* __restrict__ pidx, const int* __restrict__ lsidx,
    const float* __restrict__ ftw, const float* __restrict__ ftb,
    const float* __restrict__ l1w, const float* __restrict__ l1b,
    const float* __restrict__ l1fw, const float* __restrict__ l1fb,
    const float* __restrict__ l2w, const float* __restrict__ l2b,
    const float* __restrict__ ow, const float* __restrict__ ob,
    float* __restrict__ out)
{
    const int b = blockIdx.x;
    const int t = threadIdx.x;

    __shared__ float4 lds_acc[1540];
    __shared__ int   sidx[64];
    __shared__ float sval[64];
    __shared__ float red[4][16];
    __shared__ float l1c[16];
    __shared__ float l1x[30];

    if (t < 32)      { sidx[t] = wi[b * 32 + t];      sval[t] = wv[b * 32 + t]; }
    else if (t < 64) { sidx[t] = bi[b * 32 + t - 32]; sval[t] = bv[b * 32 + t - 32]; }
    __syncthreads();

    const int g0 = t, g1 = t + 512, g2 = t + 1024;
    const int c1 = (g1 >= 770);
    const int s0 = t;
    const int s1 = c1 ? (g1 - 770) : g1;
    const int s2 = g2 - 770;
    const bool has3 = (t < 4);
    const int s3 = 766 + t;

    const float4* fb4 = (const float4*)ftb;
    float4 a0 = fb4[s0], a1 = fb4[s1], a2 = fb4[s2];
    float4 a3 = has3 ? fb4[s3] : float4{0.f, 0.f, 0.f, 0.f};

    #pragma unroll 2
    for (int m = 0; m < 32; ++m) {
        const float4* rw = (const float4*)(ftw + (size_t)sidx[m]      * DTOT);
        const float4* rb = (const float4*)(ftw + (size_t)sidx[32 + m] * DTOT);
        const float vw = sval[m], vb = sval[32 + m];

        fma4(a0, vw, rw[s0]);
        const float4* p1 = c1 ? rb : rw;
        fma4(a1, c1 ? vb : vw, p1[s1]);
        fma4(a2, vb, rb[s2]);
        if (has3) fma4(a3, vb, rb[s3]);
    }

    lds_acc[g0] = a0;
    lds_acc[g1] = a1;
    lds_acc[g2] = a2;
    if (has3) lds_acc[1536 + t] = a3;
    __syncthreads();

    const float usv = us_arr[b];
    const float thv = them_arr[b];
    const int ls = lsidx[b];

    const float4* w1base = (const float4*)(l1w + (size_t)ls * 16 * 3072);
    const float4* w2base = (const float4*)l1fw;

    const int lane = t & 63;
    const int wave = t >> 6;

    if (t < 256) {
        float acc[16];
        #pragma unroll
        for (int k = 0; k < 16; ++k) acc[k] = 0.f;

        #pragma unroll
        for (int i = 0; i < 3; ++i) {
            const int col = t + 256 * i;
            const int q = (col >= 384) ? (col - 384) : col;
            const float4 W0 = lds_acc[q],       W1 = lds_acc[q + 384];
            const float4 B0 = lds_acc[770 + q], B1 = lds_acc[770 + q + 384];
            const float4 fv = (col >= 384)
                ? mul_scale(mix_clip(usv, thv, B0, W0), mix_clip(usv, thv, B1, W1))
                : mul_scale(mix_clip(usv, thv, W0, B0), mix_clip(usv, thv, W1, B1));
            #pragma unroll
            for (int k = 0; k < 16; ++k) {
                const float4 w1 = w1base[(size_t)k * 768 + col];
                const float4 w2 = w2base[(size_t)k * 768 + col];
                acc[k] += fv.x * (w1.x + w2.x) + fv.y * (w1.y + w2.y)
                        + fv.z * (w1.z + w2.z) + fv.w * (w1.w + w2.w);
            }
        }

        #pragma unroll
        for (int k = 0; k < 16; ++k) {
            #pragma unroll
            for (int off = 32; off > 0; off >>= 1)
                acc[k] += __shfl_xor(acc[k], off, 64);
        }
        if (lane == 0) {
            #pragma unroll
            for (int k = 0; k < 16; ++k) red[wave][k] = acc[k];
        }
    }
    __syncthreads();

    if (t < 16) {
        l1c[t] = red[0][t] + red[1][t] + red[2][t] + red[3][t]
               + l1b[ls * 16 + t] + l1fb[t];
    }
    __syncthreads();

    if (t < 15) {
        const float v = l1c[t];
        l1x[t]      = clip01(v * v * kScale);
        l1x[15 + t] = clip01(v);
    }
    __syncthreads();

    float partial = 0.f;
    if (t < 32) {
        const float* r2 = l2w + (size_t)(ls * 32 + t) * 30;
        float s2 = l2b[ls * 32 + t];
        #pragma unroll
        for (int i = 0; i < 30; ++i) s2 += l1x[i] * r2[i];
        partial = clip01(s2) * ow[ls * 32 + t];
    }
    #pragma unroll
    for (int off = 16; off > 0; off >>= 1)
        partial += __shfl_xor(partial, off, 64);

    if (t == 0) {
        const int pi = pidx[b];
        const float* pw = (const float*)&lds_acc[768];
        const float* pb = (const float*)&lds_acc[770 + 768];
        out[b] = partial + ob[ls] + l1c[15]
               + (pw[pi] - pb[pi]) * (usv - 0.5f);
    }
}

extern "C" void kernel_launch(void* const* d_in, const int* in_sizes, int n_in,
                              void* d_out, int out_size, void* d_ws, size_t ws_size,
                              hipStream_t stream) {
    const float* us   = (const float*)d_in[0];
    const float* them = (const float*)d_in[1];
    const int*   wi   = (const int*)d_in[2];
    const float* wv   = (const float*)d_in[3];
    const int*   bi   = (const int*)d_in[4];
    const float* bv   = (const float*)d_in[5];
    const int*   pidx = (const int*)d_in[6];
    const int*   ls   = (const int*)d_in[7];
    const float* ftw  = (const float*)d_in[8];
    const float* ftb  = (const float*)d_in[9];
    const float* l1w  = (const float*)d_in[10];
    const float* l1b  = (const float*)d_in[11];
    const float* l1fw = (const float*)d_in[12];
    const float* l1fb = (const float*)d_in[13];
    const float* l2w  = (const float*)d_in[14];
    const float* l2b  = (const float*)d_in[15];
    const float* ow   = (const float*)d_in[16];
    const float* ob   = (const float*)d_in[17];
    float* out = (float*)d_out;

    const int B = in_sizes[0];
    const size_t acc_bytes = (size_t)B * 1540 * 16;
    const size_t need_fp16 = TBL16_BYTES + MW_BYTES;
    const size_t cnt_off   = need_fp16 + acc_bytes;
    const size_t need_full = cnt_off + 64;

    if (ws_size >= need_full && (B & 3) == 0) {
        __half* tbl16 = (__half*)d_ws;
        float*  mw    = (float*)((char*)d_ws + TBL16_BYTES);
        float4* accw  = (float4*)((char*)d_ws + need_fp16);
        int*    cnt   = (int*)((char*)d_ws + cnt_off);
        const int NI = B / 4;                         // items per slice
        hipMemsetAsync(cnt, 0, 32, stream);
        convert_tbl<<<2048, 256, 0, stream>>>((const unsigned long long*)ftw, (uint2*)d_ws, 17346560);
        merge_l1<<<384, 256, 0, stream>>>(l1w, l1fw, mw);
        nnue_gather<<<8 * NI, 256, 0, stream>>>(wi, wv, bi, bv, tbl16, ftb, accw, cnt, NI);
        nnue_mlp<<<B, 256, 0, stream>>>(us, them, pidx, ls, accw, mw,
                                        l1b, l1fb, l2w, l2b, ow, ob, out);
    } else if (ws_size >= need_fp16) {
        __half* tbl16 = (__half*)d_ws;
        float*  mw    = (float*)((char*)d_ws + TBL16_BYTES);
        convert_tbl<<<2048, 256, 0, stream>>>((const unsigned long long*)ftw, (uint2*)d_ws, 17346560);
        merge_l1<<<384, 256, 0, stream>>>(l1w, l1fw, mw);
        nnue_fp16<<<B, 512, 0, stream>>>(us, them, wi, wv, bi, bv, pidx, ls,
                                         tbl16, ftb, mw, l1b, l1fb,
                                         l2w, l2b, ow, ob, out);
    } else {
        nnue_fused<<<B, 512, 0, stream>>>(us, them, wi, wv, bi, bv, pidx, ls,
                                          ftw, ftb, l1w, l1b, l1fw, l1fb,
                                          l2w, l2b, ow, ob, out);
    }
}

// Round 11
// 321.421 us; speedup vs baseline: 1.0869x; 1.0856x over previous
//
#include <hip/hip_runtime.h>
#include <hip/hip_fp16.h>

// NNUE fused forward — FINAL (reverted to R6 structure, the best measured).
// (K1) convert ft_weight fp32->fp16 into d_ws (139 MB; ~66 µs, HBM-BW-bound
//      floor for 416 MB of traffic).
// (K2) merge mw = l1_w + tile(l1f_w) (1.57 MB fp32, exact add, ~3 µs).
// (K3) single fused kernel per batch element (512 thr): fp16 gather-
//      accumulate whole rows -> LDS -> clipped-mix pairwise product ->
//      l1/l2/out MLP. 250 µs, jointly limited by the random-access service
//      wall: 4 structurally different gather patterns (R6/R8/R9/R10) all
//      converge to ~45-55% HBM fetch of 1.615 GB logical @ 6.5-7.1 TB/s
//      effective; per-CU load throughput sits at the measured ~10.5 B/cyc
//      ceiling while HBM is only 43% utilized.
// Numerics: fp16 table rounding dominates -> absmax 2.441e-4 (9.7x under
// the 2.36e-3 threshold). Accumulation bias-first, m-ascending, bit-stable
// across rounds. fp8/int8 fail the error budget; 2 B/elem is the floor.
// Fallback: ws too small -> R5 fp32 fused kernel.

#define DTOT 3080           // L1 + PSQT floats per ft row
#define TBL16_BYTES 138772480ull   // 22528*3080*2
#define MW_BYTES    1572864ull     // 8*16*3072*4

constexpr float kScale = 127.0f / 128.0f;

__device__ __forceinline__ float clip01(float x) { return fminf(fmaxf(x, 0.0f), 1.0f); }

__device__ __forceinline__ void fma4(float4& a, float s, const float4 v) {
    a.x += s * v.x; a.y += s * v.y; a.z += s * v.z; a.w += s * v.w;
}

__device__ __forceinline__ float4 mix_clip(float u, float th, const float4 w, const float4 b) {
    float4 r;
    r.x = clip01(u * w.x + th * b.x);
    r.y = clip01(u * w.y + th * b.y);
    r.z = clip01(u * w.z + th * b.z);
    r.w = clip01(u * w.w + th * b.w);
    return r;
}

__device__ __forceinline__ float4 mul_scale(const float4 a, const float4 b) {
    float4 r;
    r.x = a.x * b.x * kScale;
    r.y = a.y * b.y * kScale;
    r.z = a.z * b.z * kScale;
    r.w = a.w * b.w * kScale;
    return r;
}

// fp16 16-B unit accumulate; op order bit-identical to R6 (HW-validated
// at absmax 2.441e-4 in R6/R8/R9/R10).
__device__ __forceinline__ void acc_unit(float4& Aa, float4& Ab, const uint4 raw, float v) {
    const __half2* h = (const __half2*)&raw;
    const float2 q0 = __half22float2(h[0]);
    const float2 q1 = __half22float2(h[1]);
    const float2 q2 = __half22float2(h[2]);
    const float2 q3 = __half22float2(h[3]);
    Aa.x += v * q0.x; Aa.y += v * q0.y; Aa.z += v * q1.x; Aa.w += v * q1.y;
    Ab.x += v * q2.x; Ab.y += v * q2.y; Ab.z += v * q3.x; Ab.w += v * q3.y;
}

// ---------- K1: fp32 -> fp16 table conversion ----------
__global__ __launch_bounds__(256) void convert_tbl(const unsigned long long* __restrict__ in,
                                                   uint2* __restrict__ out, int n4)
{
    union Un { unsigned long long u[2]; float f[4]; };
    union Pk { __half2 h2[2]; uint2 u2; };
    for (int i = blockIdx.x * 256 + threadIdx.x; i < n4; i += gridDim.x * 256) {
        Un v;
        v.u[0] = __builtin_nontemporal_load(&in[2 * (size_t)i]);
        v.u[1] = __builtin_nontemporal_load(&in[2 * (size_t)i + 1]);
        Pk p;
        p.h2[0] = __floats2half2_rn(v.f[0], v.f[1]);
        p.h2[1] = __floats2half2_rn(v.f[2], v.f[3]);
        out[i] = p.u2;
    }
}

// ---------- K2: mw = l1_w + tile(l1f_w), float4-wise ----------
__global__ __launch_bounds__(256) void merge_l1(const float* __restrict__ l1w,
                                                const float* __restrict__ l1fw,
                                                float* __restrict__ mw)
{
    const int idx = blockIdx.x * 256 + threadIdx.x;   // 0..98303 float4s
    const float4* a = (const float4*)l1w;
    const float4* f = (const float4*)l1fw;
    float4* o = (float4*)mw;
    const int row = idx / 768;          // 0..127 = c*16+k
    const int k = row & 15;
    const int col = idx - row * 768;
    const float4 x = a[idx];
    const float4 y = f[k * 768 + col];
    float4 r;
    r.x = x.x + y.x; r.y = x.y + y.y; r.z = x.z + y.z; r.w = x.w + y.w;
    o[idx] = r;
}

// ---------- K3: fused main kernel (fp16 table, whole-row blocks) ----------
__global__ __launch_bounds__(512, 2) void nnue_fp16(
    const float* __restrict__ us_arr, const float* __restrict__ them_arr,
    const int* __restrict__ wi, const float* __restrict__ wv,
    const int* __restrict__ bi, const float* __restrict__ bv,
    const int* __restrict__ pidx, const int* __restrict__ lsidx,
    const __half* __restrict__ tbl, const float* __restrict__ ftb,
    const float* __restrict__ mw,
    const float* __restrict__ l1b, const float* __restrict__ l1fb,
    const float* __restrict__ l2w, const float* __restrict__ l2b,
    const float* __restrict__ ow, const float* __restrict__ ob,
    float* __restrict__ out)
{
    const int b = blockIdx.x;
    const int t = threadIdx.x;

    __shared__ float4 lds_acc[1540];   // white slots 0..769, black 770..1539
    __shared__ int   sidx[64];
    __shared__ float sval[64];
    __shared__ float red[4][16];
    __shared__ float l1c[16];
    __shared__ float l1x[30];

    if (t < 32)      { sidx[t] = wi[b * 32 + t];      sval[t] = wv[b * 32 + t]; }
    else if (t < 64) { sidx[t] = bi[b * 32 + t - 32]; sval[t] = bv[b * 32 + t - 32]; }
    __syncthreads();

    // 770 16-B units: unit u<385 = white pair u (slots 2u,2u+1);
    // u>=385 = black pair u-385. Thread t owns u0=t, and u1=t+512 if t<258.
    const int u0 = t;
    const bool c0 = (u0 >= 385);
    const int p0 = c0 ? (u0 - 385) : u0;
    const bool has1 = (t < 258);
    const int p1 = t + 127;            // u1 always black

    const float4* fb4 = (const float4*)ftb;
    float4 A0a = fb4[2 * p0], A0b = fb4[2 * p0 + 1];
    float4 A1a = has1 ? fb4[2 * p1] : float4{0.f, 0.f, 0.f, 0.f};
    float4 A1b = has1 ? fb4[2 * p1 + 1] : float4{0.f, 0.f, 0.f, 0.f};

    #pragma unroll 4
    for (int m = 0; m < 32; ++m) {
        const __half* rowW = tbl + (size_t)sidx[m]      * DTOT;
        const __half* rowB = tbl + (size_t)sidx[32 + m] * DTOT;
        const float vw = sval[m], vb = sval[32 + m];

        const float v0 = c0 ? vb : vw;
        const uint4 raw0 = ((const uint4*)(c0 ? rowB : rowW))[p0];
        acc_unit(A0a, A0b, raw0, v0);
        if (has1) {
            const uint4 raw1 = ((const uint4*)rowB)[p1];
            acc_unit(A1a, A1b, raw1, vb);
        }
    }

    {
        const int g0 = (c0 ? 770 : 0) + 2 * p0;
        lds_acc[g0] = A0a; lds_acc[g0 + 1] = A0b;
        if (has1) {
            const int g1 = 770 + 2 * p1;
            lds_acc[g1] = A1a; lds_acc[g1 + 1] = A1b;
        }
    }
    __syncthreads();

    const float usv = us_arr[b];
    const float thv = them_arr[b];
    const int ls = lsidx[b];
    const float4* mwbase = (const float4*)mw + (size_t)ls * 16 * 768;

    const int lane = t & 63;
    const int wave = t >> 6;

    if (t < 256) {
        float4 fvv[3];
        #pragma unroll
        for (int i = 0; i < 3; ++i) {
            const int col = t + 256 * i;
            const int q = (col >= 384) ? (col - 384) : col;   // 384 != pow2!
            const float4 W0 = lds_acc[q],       W1 = lds_acc[q + 384];
            const float4 B0 = lds_acc[770 + q], B1 = lds_acc[770 + q + 384];
            fvv[i] = (col >= 384)
                ? mul_scale(mix_clip(usv, thv, B0, W0), mix_clip(usv, thv, B1, W1))
                : mul_scale(mix_clip(usv, thv, W0, B0), mix_clip(usv, thv, W1, B1));
        }

        #pragma unroll
        for (int half = 0; half < 2; ++half) {
            float acck[8];
            #pragma unroll
            for (int k = 0; k < 8; ++k) acck[k] = 0.f;

            #pragma unroll
            for (int i = 0; i < 3; ++i) {
                const int col = t + 256 * i;
                const float4 fv = fvv[i];
                #pragma unroll
                for (int k = 0; k < 8; ++k) {
                    const float4 w1 = mwbase[(size_t)(half * 8 + k) * 768 + col];
                    acck[k] += fv.x * w1.x + fv.y * w1.y + fv.z * w1.z + fv.w * w1.w;
                }
            }

            #pragma unroll
            for (int k = 0; k < 8; ++k) {
                #pragma unroll
                for (int off = 32; off > 0; off >>= 1)
                    acck[k] += __shfl_xor(acck[k], off, 64);
            }
            if (lane == 0) {
                #pragma unroll
                for (int k = 0; k < 8; ++k) red[wave][half * 8 + k] = acck[k];
            }
        }
    }
    __syncthreads();

    if (t < 16) {
        l1c[t] = red[0][t] + red[1][t] + red[2][t] + red[3][t]
               + l1b[ls * 16 + t] + l1fb[t];
    }
    __syncthreads();

    if (t < 15) {
        const float v = l1c[t];
        l1x[t]      = clip01(v * v * kScale);
        l1x[15 + t] = clip01(v);
    }
    __syncthreads();

    float partial = 0.f;
    if (t < 32) {
        const float* r2 = l2w + (size_t)(ls * 32 + t) * 30;
        float s2 = l2b[ls * 32 + t];
        #pragma unroll
        for (int i = 0; i < 30; ++i) s2 += l1x[i] * r2[i];
        partial = clip01(s2) * ow[ls * 32 + t];
    }
    #pragma unroll
    for (int off = 16; off > 0; off >>= 1)
        partial += __shfl_xor(partial, off, 64);

    if (t == 0) {
        const int pi = pidx[b];
        const float* pw = (const float*)&lds_acc[768];        // white psqt
        const float* pb = (const float*)&lds_acc[770 + 768];  // black psqt
        out[b] = partial + ob[ls] + l1c[15]
               + (pw[pi] - pb[pi]) * (usv - 0.5f);
    }
}

// ---------- Fallback: R5 fp32 fused kernel (no workspace needed) ----------
__global__ __launch_bounds__(512, 2) void nnue_fused(
    const float* __restrict__ us_arr, const float* __restrict__ them_arr,
    const int* __restrict__ wi, const float* __restrict__ wv,
    const int* __restrict__ bi, const float* __restrict__ bv,
    const int* __restrict__ pidx, const int* __restrict__ lsidx,
    const float* __restrict__ ftw, const float* __restrict__ ftb,
    const float* __restrict__ l1w, const float* __restrict__ l1b,
    const float* __restrict__ l1fw, const float* __restrict__ l1fb,
    const float* __restrict__ l2w, const float* __restrict__ l2b,
    const float* __restrict__ ow, const float* __restrict__ ob,
    float* __restrict__ out)
{
    const int b = blockIdx.x;
    const int t = threadIdx.x;

    __shared__ float4 lds_acc[1540];
    __shared__ int   sidx[64];
    __shared__ float sval[64];
    __shared__ float red[4][16];
    __shared__ float l1c[16];
    __shared__ float l1x[30];

    if (t < 32)      { sidx[t] = wi[b * 32 + t];      sval[t] = wv[b * 32 + t]; }
    else if (t < 64) { sidx[t] = bi[b * 32 + t - 32]; sval[t] = bv[b * 32 + t - 32]; }
    __syncthreads();

    const int g0 = t, g1 = t + 512, g2 = t + 1024;
    const int c1 = (g1 >= 770);
    const int s0 = t;
    const int s1 = c1 ? (g1 - 770) : g1;
    const int s2 = g2 - 770;
    const bool has3 = (t < 4);
    const int s3 = 766 + t;

    const float4* fb4 = (const float4*)ftb;
    float4 a0 = fb4[s0], a1 = fb4[s1], a2 = fb4[s2];
    float4 a3 = has3 ? fb4[s3] : float4{0.f, 0.f, 0.f, 0.f};

    #pragma unroll 2
    for (int m = 0; m < 32; ++m) {
        const float4* rw = (const float4*)(ftw + (size_t)sidx[m]      * DTOT);
        const float4* rb = (const float4*)(ftw + (size_t)sidx[32 + m] * DTOT);
        const float vw = sval[m], vb = sval[32 + m];

        fma4(a0, vw, rw[s0]);
        const float4* p1 = c1 ? rb : rw;
        fma4(a1, c1 ? vb : vw, p1[s1]);
        fma4(a2, vb, rb[s2]);
        if (has3) fma4(a3, vb, rb[s3]);
    }

    lds_acc[g0] = a0;
    lds_acc[g1] = a1;
    lds_acc[g2] = a2;
    if (has3) lds_acc[1536 + t] = a3;
    __syncthreads();

    const float usv = us_arr[b];
    const float thv = them_arr[b];
    const int ls = lsidx[b];

    const float4* w1base = (const float4*)(l1w + (size_t)ls * 16 * 3072);
    const float4* w2base = (const float4*)l1fw;

    const int lane = t & 63;
    const int wave = t >> 6;

    if (t < 256) {
        float acc[16];
        #pragma unroll
        for (int k = 0; k < 16; ++k) acc[k] = 0.f;

        #pragma unroll
        for (int i = 0; i < 3; ++i) {
            const int col = t + 256 * i;
            const int q = (col >= 384) ? (col - 384) : col;
            const float4 W0 = lds_acc[q],       W1 = lds_acc[q + 384];
            const float4 B0 = lds_acc[770 + q], B1 = lds_acc[770 + q + 384];
            const float4 fv = (col >= 384)
                ? mul_scale(mix_clip(usv, thv, B0, W0), mix_clip(usv, thv, B1, W1))
                : mul_scale(mix_clip(usv, thv, W0, B0), mix_clip(usv, thv, W1, B1));
            #pragma unroll
            for (int k = 0; k < 16; ++k) {
                const float4 w1 = w1base[(size_t)k * 768 + col];
                const float4 w2 = w2base[(size_t)k * 768 + col];
                acc[k] += fv.x * (w1.x + w2.x) + fv.y * (w1.y + w2.y)
                        + fv.z * (w1.z + w2.z) + fv.w * (w1.w + w2.w);
            }
        }

        #pragma unroll
        for (int k = 0; k < 16; ++k) {
            #pragma unroll
            for (int off = 32; off > 0; off >>= 1)
                acc[k] += __shfl_xor(acc[k], off, 64);
        }
        if (lane == 0) {
            #pragma unroll
            for (int k = 0; k < 16; ++k) red[wave][k] = acc[k];
        }
    }
    __syncthreads();

    if (t < 16) {
        l1c[t] = red[0][t] + red[1][t] + red[2][t] + red[3][t]
               + l1b[ls * 16 + t] + l1fb[t];
    }
    __syncthreads();

    if (t < 15) {
        const float v = l1c[t];
        l1x[t]      = clip01(v * v * kScale);
        l1x[15 + t] = clip01(v);
    }
    __syncthreads();

    float partial = 0.f;
    if (t < 32) {
        const float* r2 = l2w + (size_t)(ls * 32 + t) * 30;
        float s2 = l2b[ls * 32 + t];
        #pragma unroll
        for (int i = 0; i < 30; ++i) s2 += l1x[i] * r2[i];
        partial = clip01(s2) * ow[ls * 32 + t];
    }
    #pragma unroll
    for (int off = 16; off > 0; off >>= 1)
        partial += __shfl_xor(partial, off, 64);

    if (t == 0) {
        const int pi = pidx[b];
        const float* pw = (const float*)&lds_acc[768];
        const float* pb = (const float*)&lds_acc[770 + 768];
        out[b] = partial + ob[ls] + l1c[15]
               + (pw[pi] - pb[pi]) * (usv - 0.5f);
    }
}

extern "C" void kernel_launch(void* const* d_in, const int* in_sizes, int n_in,
                              void* d_out, int out_size, void* d_ws, size_t ws_size,
                              hipStream_t stream) {
    const float* us   = (const float*)d_in[0];
    const float* them = (const float*)d_in[1];
    const int*   wi   = (const int*)d_in[2];
    const float* wv   = (const float*)d_in[3];
    const int*   bi   = (const int*)d_in[4];
    const float* bv   = (const float*)d_in[5];
    const int*   pidx = (const int*)d_in[6];
    const int*   ls   = (const int*)d_in[7];
    const float* ftw  = (const float*)d_in[8];
    const float* ftb  = (const float*)d_in[9];
    const float* l1w  = (const float*)d_in[10];
    const float* l1b  = (const float*)d_in[11];
    const float* l1fw = (const float*)d_in[12];
    const float* l1fb = (const float*)d_in[13];
    const float* l2w  = (const float*)d_in[14];
    const float* l2b  = (const float*)d_in[15];
    const float* ow   = (const float*)d_in[16];
    const float* ob   = (const float*)d_in[17];
    float* out = (float*)d_out;

    const int B = in_sizes[0];
    const size_t need_fp16 = TBL16_BYTES + MW_BYTES;

    if (ws_size >= need_fp16) {
        __half* tbl16 = (__half*)d_ws;
        float*  mw    = (float*)((char*)d_ws + TBL16_BYTES);
        convert_tbl<<<2048, 256, 0, stream>>>((const unsigned long long*)ftw, (uint2*)d_ws, 17346560);
        merge_l1<<<384, 256, 0, stream>>>(l1w, l1fw, mw);
        nnue_fp16<<<B, 512, 0, stream>>>(us, them, wi, wv, bi, bv, pidx, ls,
                                         tbl16, ftb, mw, l1b, l1fb,
                                         l2w, l2b, ow, ob, out);
    } else {
        nnue_fused<<<B, 512, 0, stream>>>(us, them, wi, wv, bi, bv, pidx, ls,
                                          ftw, ftb, l1w, l1b, l1fw, l1fb,
                                          l2w, l2b, ow, ob, out);
    }
}